// Round 2
// baseline (1746.050 us; speedup 1.0000x reference)
//
#include <hip/hip_runtime.h>
#include <hip/hip_bf16.h>
#include <math.h>

// Problem: STAttentionBlock  N=32 C=64 T=400 V=27 S=2 IC=16
// I/O dtype: float32 (reference is pure jnp.float32). Internal compute: f32.

typedef __hip_bfloat16 bf16;

#define NN 32
#define CH 64
#define TT 400
#define VV 27
#define PIX 10800            // T*V
#define NSUV (32*2*27*27)    // 46656
#define XTOT (NN*CH*PIX)     // 22118400

__device__ __forceinline__ float lrelu(float x) { return x >= 0.f ? x : 0.1f * x; }

// storage helpers for y2 (f32 preferred, bf16 fallback if ws too small)
__device__ __forceinline__ void st_y(float* p, float v) { *p = v; }
__device__ __forceinline__ void st_y(bf16* p, float v) { *p = __float2bfloat16(v); }
__device__ __forceinline__ float ld_y(const float* p) { return *p; }
__device__ __forceinline__ float ld_y(const bf16* p) { return __bfloat162float(*p); }

// ---------------------------------------------------------------------------
// Kernel 1: fused (x+pe) -> Q/K projection -> partial score accumulation.
// grid (8 t-chunks, S=2, N=32), block 256. Scores accumulated via atomicAdd.
// ---------------------------------------------------------------------------
__global__ __launch_bounds__(256) void k_scores(
    const float* __restrict__ x, const float* __restrict__ w_in,
    const float* __restrict__ b_in, float* __restrict__ scores)
{
    const int tid = threadIdx.x;
    const int tc = blockIdx.x;   // t-chunk 0..7 (50 t each)
    const int s  = blockIdx.y;
    const int n  = blockIdx.z;

    __shared__ float wq[16 * 64], wk[16 * 64];
    __shared__ float pe[64 * 27], xs[64 * 27];
    __shared__ float qs[16 * 27], ks[16 * 27];
    __shared__ float bq[16], bk[16];

    for (int idx = tid; idx < 1024; idx += 256) {
        int c = idx >> 6, cc = idx & 63;
        wq[idx] = w_in[(s * 16 + c) * 64 + cc];
        wk[idx] = w_in[(32 + s * 16 + c) * 64 + cc];
    }
    for (int idx = tid; idx < 64 * 27; idx += 256) {
        int c = idx / 27, u = idx % 27;
        int i = c >> 1;
        // div_i = exp(-(2i)*ln(10000)/64) = exp(-i * 0.287823136624...)
        float div = expf(-0.28782313662425575f * (float)i);
        float ang = div * (float)u;
        pe[idx] = (c & 1) ? cosf(ang) : sinf(ang);
    }
    if (tid < 16) {
        bq[tid] = b_in[s * 16 + tid];
        bk[tid] = b_in[32 + s * 16 + tid];
    }
    __syncthreads();

    const int u0 = tid / 27, v0 = tid % 27;
    const int p1 = tid + 256, u1 = p1 / 27, v1 = p1 % 27;
    const int p2 = tid + 512, u2 = p2 / 27, v2 = p2 % 27;
    const bool has2 = (p2 < 729);
    float a0 = 0.f, a1 = 0.f, a2 = 0.f;

    for (int t = tc * 50; t < tc * 50 + 50; ++t) {
        for (int idx = tid; idx < 64 * 27; idx += 256) {
            int c = idx / 27, u = idx % 27;
            xs[idx] = x[(n * 64 + c) * PIX + t * 27 + u] + pe[idx];
        }
        __syncthreads();
        for (int idx = tid; idx < 864; idx += 256) {
            int h = idx;
            if (h < 432) {
                int c = h / 27, u = h % 27;
                float acc = bq[c];
                const float* w = &wq[c * 64];
                #pragma unroll
                for (int cc = 0; cc < 64; ++cc) acc += w[cc] * xs[cc * 27 + u];
                qs[h] = acc;
            } else {
                h -= 432;
                int c = h / 27, u = h % 27;
                float acc = bk[c];
                const float* w = &wk[c * 64];
                #pragma unroll
                for (int cc = 0; cc < 64; ++cc) acc += w[cc] * xs[cc * 27 + u];
                ks[h] = acc;
            }
        }
        __syncthreads();
        #pragma unroll
        for (int c = 0; c < 16; ++c) {
            a0 += qs[c * 27 + u0] * ks[c * 27 + v0];
            a1 += qs[c * 27 + u1] * ks[c * 27 + v1];
            if (has2) a2 += qs[c * 27 + u2] * ks[c * 27 + v2];
        }
        __syncthreads();
    }
    float* sb = scores + (n * 2 + s) * 729;
    atomicAdd(&sb[tid], a0);
    atomicAdd(&sb[p1], a1);
    if (has2) atomicAdd(&sb[p2], a2);
}

// ---------------------------------------------------------------------------
// Kernel 2: att = tanh(scores/(IC*T)) * alpha_s + att0
// ---------------------------------------------------------------------------
__global__ void k_att(const float* __restrict__ scores,
                      const float* __restrict__ alphas,
                      const float* __restrict__ att0,
                      float* __restrict__ att)
{
    int i = blockIdx.x * 256 + threadIdx.x;
    if (i >= NSUV) return;
    int r = i % 1458;           // s*729 + u*27 + v
    int s = r / 729;
    att[i] = tanhf(scores[i] * (1.f / 6400.f)) * alphas[s] + att0[r];
}

// ---------------------------------------------------------------------------
// Kernel 3: fused attention-apply + w_outs conv + BN + res + leaky
//           + w_ff conv + BN + res + leaky  -> y2 (ws)
// grid (T, N), block 256. Everything pointwise in t.
// ---------------------------------------------------------------------------
template <typename YT>
__global__ __launch_bounds__(256) void k_cde(
    const float* __restrict__ x, const float* __restrict__ att,
    const float* __restrict__ w_outs, const float* __restrict__ b_outs,
    const float* __restrict__ go1, const float* __restrict__ bo1,
    const float* __restrict__ mo1, const float* __restrict__ vo1,
    const float* __restrict__ w_ff, const float* __restrict__ b_ff,
    const float* __restrict__ gf2, const float* __restrict__ bf2,
    const float* __restrict__ mf2, const float* __restrict__ vf2,
    YT* __restrict__ y2out)
{
    const int tid = threadIdx.x;
    const int t = blockIdx.x, n = blockIdx.y;

    __shared__ float xs[1728];   // x[n,:,t,:]  (original x, no PE)
    __shared__ float al[1458];   // att[n,:,:,:]
    __shared__ float mm[3456];   // m[j= s*64+c][v]
    __shared__ float o1[1728];   // intermediate y after first conv block

    for (int idx = tid; idx < 1728; idx += 256)
        xs[idx] = x[(n * 64 + idx / 27) * PIX + t * 27 + idx % 27];
    for (int idx = tid; idx < 1458; idx += 256)
        al[idx] = att[n * 1458 + idx];
    __syncthreads();

    // m[s,c,v] = sum_u x[c,u] * att[s,u,v]
    for (int idx = tid; idx < 3456; idx += 256) {
        int j = idx / 27, v = idx % 27;
        int s = j >> 6, c = j & 63;
        const float* xr = &xs[c * 27];
        const float* ar = &al[s * 729 + v];
        float acc = 0.f;
        #pragma unroll
        for (int u = 0; u < 27; ++u) acc += xr[u] * ar[u * 27];
        mm[idx] = acc;
    }
    __syncthreads();

    // o1[o,v] = leaky(x + bn(sum_j w_outs[o,j]*m[j,v] + b_outs[o]))
    for (int idx = tid; idx < 1728; idx += 256) {
        int o = idx / 27, v = idx % 27;
        float acc = 0.f;
        const float* w = &w_outs[o * 128];
        #pragma unroll 8
        for (int j = 0; j < 128; ++j) acc += w[j] * mm[j * 27 + v];
        float inv = go1[o] * rsqrtf(vo1[o] + 1e-5f);
        float val = (acc + b_outs[o]) * inv + (bo1[o] - mo1[o] * inv);
        o1[idx] = lrelu(xs[idx] + val);
    }
    __syncthreads();

    // y2[o,v] = leaky(x + bn(sum_c w_ff[o,c]*o1[c,v] + b_ff[o]))
    for (int idx = tid; idx < 1728; idx += 256) {
        int o = idx / 27, v = idx % 27;
        float acc = 0.f;
        const float* w = &w_ff[o * 64];
        #pragma unroll 8
        for (int c = 0; c < 64; ++c) acc += w[c] * o1[c * 27 + v];
        float inv = gf2[o] * rsqrtf(vf2[o] + 1e-5f);
        float val = (acc + b_ff[o]) * inv + (bf2[o] - mf2[o] * inv);
        val = lrelu(xs[idx] + val);
        st_y(&y2out[(n * 64 + o) * PIX + t * 27 + v], val);
    }
}

// ---------------------------------------------------------------------------
// Kernel 4: temporal 3x1 conv + BN + residual + leaky -> output (f32)
// grid (T, N), block 256.
// ---------------------------------------------------------------------------
template <typename YT>
__global__ __launch_bounds__(256) void k_tconv(
    const YT* __restrict__ y2in, const float* __restrict__ w_t,
    const float* __restrict__ b_t,
    const float* __restrict__ gt, const float* __restrict__ bt,
    const float* __restrict__ mt, const float* __restrict__ vt,
    float* __restrict__ out)
{
    const int tid = threadIdx.x;
    const int t = blockIdx.x, n = blockIdx.y;

    __shared__ float yt[3 * 1728];   // y2[n,:,t-1..t+1,:]

    for (int idx = tid; idx < 5184; idx += 256) {
        int kt = idx / 1728, r = idx % 1728;
        int c = r / 27, v = r % 27;
        int tt = t + kt - 1;
        yt[idx] = (tt >= 0 && tt < TT)
                    ? ld_y(&y2in[(n * 64 + c) * PIX + tt * 27 + v]) : 0.f;
    }
    __syncthreads();

    for (int idx = tid; idx < 1728; idx += 256) {
        int o = idx / 27, v = idx % 27;
        float acc = 0.f;
        const float* w = &w_t[o * 192];   // w_t[o][c][kt], kt fastest
        #pragma unroll 4
        for (int c = 0; c < 64; ++c) {
            float ya = yt[c * 27 + v];
            float yb = yt[1728 + c * 27 + v];
            float yc = yt[3456 + c * 27 + v];
            acc += w[c * 3 + 0] * ya + w[c * 3 + 1] * yb + w[c * 3 + 2] * yc;
        }
        float inv = gt[o] * rsqrtf(vt[o] + 1e-5f);
        float val = (acc + b_t[o]) * inv + (bt[o] - mt[o] * inv);
        val = lrelu(yt[1728 + idx] + val);
        out[(n * 64 + o) * PIX + t * 27 + v] = val;
    }
}

// ---------------------------------------------------------------------------
extern "C" void kernel_launch(void* const* d_in, const int* in_sizes, int n_in,
                              void* d_out, int out_size, void* d_ws, size_t ws_size,
                              hipStream_t stream)
{
    const float* x      = (const float*)d_in[0];
    const float* w_in   = (const float*)d_in[1];
    const float* b_in   = (const float*)d_in[2];
    const float* alphas = (const float*)d_in[3];
    const float* att0   = (const float*)d_in[4];
    const float* w_outs = (const float*)d_in[5];
    const float* b_outs = (const float*)d_in[6];
    const float* bog    = (const float*)d_in[7];
    const float* bob    = (const float*)d_in[8];
    const float* bom    = (const float*)d_in[9];
    const float* bov    = (const float*)d_in[10];
    const float* w_ff   = (const float*)d_in[11];
    const float* b_ff   = (const float*)d_in[12];
    const float* bfg    = (const float*)d_in[13];
    const float* bfb    = (const float*)d_in[14];
    const float* bfm    = (const float*)d_in[15];
    const float* bfv    = (const float*)d_in[16];
    const float* w_t    = (const float*)d_in[17];
    const float* b_t    = (const float*)d_in[18];
    const float* btg    = (const float*)d_in[19];
    const float* btb    = (const float*)d_in[20];
    const float* btm    = (const float*)d_in[21];
    const float* btv    = (const float*)d_in[22];

    // workspace layout: scores (f32) | att (f32) | y2 (f32 preferred, bf16 fallback)
    float* scores = (float*)d_ws;
    float* att    = scores + NSUV;
    void*  y2     = (void*)(att + NSUV);

    const size_t need_f32 = (size_t)(2 * NSUV) * 4 + (size_t)XTOT * 4;
    const bool y2_f32 = (ws_size >= need_f32);

    hipMemsetAsync(scores, 0, NSUV * sizeof(float), stream);

    k_scores<<<dim3(8, 2, NN), 256, 0, stream>>>(x, w_in, b_in, scores);
    k_att<<<(NSUV + 255) / 256, 256, 0, stream>>>(scores, alphas, att0, att);
    if (y2_f32) {
        k_cde<float><<<dim3(TT, NN), 256, 0, stream>>>(x, att, w_outs, b_outs,
                                                bog, bob, bom, bov,
                                                w_ff, b_ff, bfg, bfb, bfm, bfv,
                                                (float*)y2);
        k_tconv<float><<<dim3(TT, NN), 256, 0, stream>>>((const float*)y2, w_t, b_t,
                                                btg, btb, btm, btv, (float*)d_out);
    } else {
        k_cde<bf16><<<dim3(TT, NN), 256, 0, stream>>>(x, att, w_outs, b_outs,
                                                bog, bob, bom, bov,
                                                w_ff, b_ff, bfg, bfb, bfm, bfv,
                                                (bf16*)y2);
        k_tconv<bf16><<<dim3(TT, NN), 256, 0, stream>>>((const bf16*)y2, w_t, b_t,
                                                btg, btb, btm, btv, (float*)d_out);
    }
}

// Round 3
// 1275.272 us; speedup vs baseline: 1.3692x; 1.3692x over previous
//
#include <hip/hip_runtime.h>
#include <hip/hip_bf16.h>
#include <math.h>

// STAttentionBlock  N=32 C=64 T=400 V=27 S=2 IC=16 — f32 I/O, f32 compute.
// Round 3: register-tiled (2o x 4v) f32 GEMM stages, float4 LDS reads,
// PE absorbed into projection bias, k_scores at 1600 blocks.

typedef __hip_bfloat16 bf16;

#define NN 32
#define CH 64
#define TT 400
#define VV 27
#define PIX 10800            // T*V
#define NSUV (32*2*27*27)    // 46656
#define XTOT (NN*CH*PIX)     // 22118400

__device__ __forceinline__ float lrelu(float x) { return x >= 0.f ? x : 0.1f * x; }
__device__ __forceinline__ float4 ld4(const float* p) { return *reinterpret_cast<const float4*>(p); }
__device__ __forceinline__ void st4(float* p, float4 v) { *reinterpret_cast<float4*>(p) = v; }
#define FMA4(A, S, V) { (A).x += (S)*(V).x; (A).y += (S)*(V).y; (A).z += (S)*(V).z; (A).w += (S)*(V).w; }

__device__ __forceinline__ void st_y(float* p, float v) { *p = v; }
__device__ __forceinline__ void st_y(bf16* p, float v) { *p = __float2bfloat16(v); }
__device__ __forceinline__ float ld_y(const float* p) { return *p; }
__device__ __forceinline__ float ld_y(const bf16* p) { return __bfloat162float(*p); }

// ---------------------------------------------------------------------------
// k_pbias: pb[s][qk][c][u] = b_in + sum_cc w_in * pe[cc][u]  (PE absorbed)
// one block; padded u-dim 28, pad = 0.
// ---------------------------------------------------------------------------
__global__ __launch_bounds__(256) void k_pbias(
    const float* __restrict__ w_in, const float* __restrict__ b_in,
    float* __restrict__ pb)
{
    __shared__ float pe[64 * 27];
    const int tid = threadIdx.x;
    for (int idx = tid; idx < 1728; idx += 256) {
        int c = idx / 27, u = idx % 27;
        float div = expf(-0.28782313662425575f * (float)(c >> 1));
        float ang = div * (float)u;
        pe[idx] = (c & 1) ? cosf(ang) : sinf(ang);
    }
    __syncthreads();
    for (int idx = tid; idx < 1792; idx += 256) {   // 2s*2qk*16c*28u
        int u = idx % 28, r = idx / 28;
        int c = r % 16, sq = r / 16;                // sq = s*2+qk
        if (u >= 27) { pb[idx] = 0.f; continue; }
        int s = sq >> 1, qk = sq & 1;
        int row = qk * 32 + s * 16 + c;
        float acc = b_in[row];
        for (int cc = 0; cc < 64; ++cc) acc += w_in[row * 64 + cc] * pe[cc * 27 + u];
        pb[idx] = acc;
    }
}

// ---------------------------------------------------------------------------
// k_scores: grid (25 tchunks, 2 s, 32 n), 16 t per block, 2 t per iteration.
// proj: q/k = W * x + pb (reg tile 2c x 4u); scores: q^T k (tile 1u x 4v).
// ---------------------------------------------------------------------------
__global__ __launch_bounds__(256) void k_scores(
    const float* __restrict__ x, const float* __restrict__ w_in,
    const float* __restrict__ pb, float* __restrict__ scores)
{
    const int tid = threadIdx.x;
    const int s = blockIdx.y, n = blockIdx.z;
    const int t0 = blockIdx.x * 16;

    __shared__ __align__(16) float wq[16 * 68], wk[16 * 68];   // +4 row pad
    __shared__ __align__(16) float pbs[2 * 16 * 28];
    __shared__ __align__(16) float xss[2 * 64 * 28];
    __shared__ __align__(16) float qkb[4 * 16 * 28];           // [(t2*2+qk)*16+c][u]

    for (int idx = tid; idx < 1024; idx += 256) {
        int c = idx >> 6, cc = idx & 63;
        wq[c * 68 + cc] = w_in[(s * 16 + c) * 64 + cc];
        wk[c * 68 + cc] = w_in[(32 + s * 16 + c) * 64 + cc];
    }
    for (int idx = tid; idx < 896; idx += 256)
        pbs[idx] = pb[s * 896 + idx];

    // proj mapping (tid < 224)
    const int pug = tid % 7, pcg = (tid / 7) % 8, pqk = (tid / 56) & 1, pt2 = tid / 112;
    // score mapping (tid < 189)
    const int su = tid / 7, svg = tid % 7;
    float4 sacc = {0.f, 0.f, 0.f, 0.f};

    for (int tp = 0; tp < 8; ++tp) {
        __syncthreads();
        for (int idx = tid; idx < 3456; idx += 256) {
            int t2 = idx / 1728, r = idx - t2 * 1728;
            int c = r / 27, u = r - c * 27;
            xss[(t2 * 64 + c) * 28 + u] = x[(n * 64 + c) * PIX + (t0 + tp * 2 + t2) * 27 + u];
        }
        __syncthreads();
        if (tid < 224) {
            const float* wsel = pqk ? wk : wq;
            const float* xb = &xss[pt2 * 64 * 28];
            const int c0 = pcg * 2, u0 = pug * 4;
            float4 a0 = {0,0,0,0}, a1 = {0,0,0,0};
            #pragma unroll
            for (int cc4 = 0; cc4 < 16; ++cc4) {
                float4 w0 = ld4(&wsel[c0 * 68 + cc4 * 4]);
                float4 w1 = ld4(&wsel[(c0 + 1) * 68 + cc4 * 4]);
                float4 xv;
                xv = ld4(&xb[(cc4 * 4 + 0) * 28 + u0]); FMA4(a0, w0.x, xv); FMA4(a1, w1.x, xv);
                xv = ld4(&xb[(cc4 * 4 + 1) * 28 + u0]); FMA4(a0, w0.y, xv); FMA4(a1, w1.y, xv);
                xv = ld4(&xb[(cc4 * 4 + 2) * 28 + u0]); FMA4(a0, w0.z, xv); FMA4(a1, w1.z, xv);
                xv = ld4(&xb[(cc4 * 4 + 3) * 28 + u0]); FMA4(a0, w0.w, xv); FMA4(a1, w1.w, xv);
            }
            float4 p0 = ld4(&pbs[(pqk * 16 + c0) * 28 + u0]);
            float4 p1 = ld4(&pbs[(pqk * 16 + c0 + 1) * 28 + u0]);
            a0.x += p0.x; a0.y += p0.y; a0.z += p0.z; a0.w += p0.w;
            a1.x += p1.x; a1.y += p1.y; a1.z += p1.z; a1.w += p1.w;
            float* qo = &qkb[((pt2 * 2 + pqk) * 16) * 28];
            st4(&qo[c0 * 28 + u0], a0);
            st4(&qo[(c0 + 1) * 28 + u0], a1);
        }
        __syncthreads();
        if (tid < 189) {
            #pragma unroll
            for (int t2 = 0; t2 < 2; ++t2) {
                const float* qb = &qkb[(t2 * 2 + 0) * 16 * 28];
                const float* kb = &qkb[(t2 * 2 + 1) * 16 * 28];
                #pragma unroll
                for (int c = 0; c < 16; ++c) {
                    float qv = qb[c * 28 + su];
                    float4 kv = ld4(&kb[c * 28 + svg * 4]);
                    FMA4(sacc, qv, kv);
                }
            }
        }
    }
    if (tid < 189) {
        float* sb = scores + (n * 2 + s) * 729 + su * 27 + svg * 4;
        if (svg * 4 + 0 < 27) atomicAdd(&sb[0], sacc.x);
        if (svg * 4 + 1 < 27) atomicAdd(&sb[1], sacc.y);
        if (svg * 4 + 2 < 27) atomicAdd(&sb[2], sacc.z);
        if (svg * 4 + 3 < 27) atomicAdd(&sb[3], sacc.w);
    }
}

// ---------------------------------------------------------------------------
// k_att: att = tanh(scores/(IC*T)) * alpha_s + att0
// ---------------------------------------------------------------------------
__global__ void k_att(const float* __restrict__ scores,
                      const float* __restrict__ alphas,
                      const float* __restrict__ att0,
                      float* __restrict__ att)
{
    int i = blockIdx.x * 256 + threadIdx.x;
    if (i >= NSUV) return;
    int r = i % 1458;
    int s = r / 729;
    att[i] = tanhf(scores[i] * (1.f / 6400.f)) * alphas[s] + att0[r];
}

// ---------------------------------------------------------------------------
// k_cde: per (t,n): attention-apply -> conv(w_outs)+BN+res+leaky
//        -> conv(w_ff)+BN+res+leaky -> y2. Register tile 2o x 4v.
// ---------------------------------------------------------------------------
template <typename YT>
__global__ __launch_bounds__(256) void k_cde(
    const float* __restrict__ x, const float* __restrict__ att,
    const float* __restrict__ w_outs, const float* __restrict__ b_outs,
    const float* __restrict__ go1, const float* __restrict__ bo1,
    const float* __restrict__ mo1, const float* __restrict__ vo1,
    const float* __restrict__ w_ff, const float* __restrict__ b_ff,
    const float* __restrict__ gf2, const float* __restrict__ bf2,
    const float* __restrict__ mf2, const float* __restrict__ vf2,
    YT* __restrict__ y2out)
{
    const int tid = threadIdx.x;
    const int t = blockIdx.x, n = blockIdx.y;

    __shared__ __align__(16) float xs[64 * 29];     // stride 29: scalar-read friendly
    __shared__ __align__(16) float alp[2 * 27 * 28];
    __shared__ __align__(16) float mm[128 * 28];
    __shared__ __align__(16) float o1[64 * 28];
    __shared__ __align__(16) float wbuf[64 * 68];   // [row][64 + pad4]

    for (int idx = tid; idx < 1728; idx += 256) {
        int c = idx / 27, v = idx - c * 27;
        xs[c * 29 + v] = x[(n * 64 + c) * PIX + t * 27 + v];
    }
    for (int idx = tid; idx < 1458; idx += 256) {
        int s = idx / 729, r = idx - s * 729;
        int u = r / 27, v = r - u * 27;
        alp[(s * 27 + u) * 28 + v] = att[n * 1458 + idx];
    }
    for (int idx = tid; idx < 54; idx += 256) alp[idx * 28 + 27] = 0.f;
    for (int idx = tid; idx < 4096; idx += 256)
        wbuf[(idx >> 6) * 68 + (idx & 63)] = w_outs[(idx >> 6) * 128 + (idx & 63)];
    __syncthreads();

    const int vg = tid % 7, grp = tid / 7;          // grp < 32 for tid < 224
    const int vo = vg * 4;

    // ---- mm stage: tile 4j x 4v ----
    if (tid < 224) {
        const int j0 = grp * 4, ss = j0 >> 6, c0 = j0 & 63;
        const float* ab = &alp[ss * 27 * 28];
        float4 m0 = {0,0,0,0}, m1 = {0,0,0,0}, m2 = {0,0,0,0}, m3 = {0,0,0,0};
        #pragma unroll
        for (int u = 0; u < 27; ++u) {
            float4 av = ld4(&ab[u * 28 + vo]);
            FMA4(m0, xs[(c0 + 0) * 29 + u], av);
            FMA4(m1, xs[(c0 + 1) * 29 + u], av);
            FMA4(m2, xs[(c0 + 2) * 29 + u], av);
            FMA4(m3, xs[(c0 + 3) * 29 + u], av);
        }
        st4(&mm[(j0 + 0) * 28 + vo], m0);
        st4(&mm[(j0 + 1) * 28 + vo], m1);
        st4(&mm[(j0 + 2) * 28 + vo], m2);
        st4(&mm[(j0 + 3) * 28 + vo], m3);
    }
    __syncthreads();

    // ---- o1 stage: tile 2o x 4v, K=128 in 2 chunks of 64 ----
    const int o0 = grp * 2, oo1 = o0 + 1;
    float4 acc0 = {0,0,0,0}, acc1 = {0,0,0,0};
    for (int jc = 0; jc < 2; ++jc) {
        if (jc == 1) {
            __syncthreads();
            for (int idx = tid; idx < 4096; idx += 256)
                wbuf[(idx >> 6) * 68 + (idx & 63)] = w_outs[(idx >> 6) * 128 + 64 + (idx & 63)];
            __syncthreads();
        }
        if (tid < 224) {
            #pragma unroll
            for (int j4 = 0; j4 < 16; ++j4) {
                float4 wa = ld4(&wbuf[o0 * 68 + j4 * 4]);
                float4 wb = ld4(&wbuf[oo1 * 68 + j4 * 4]);
                const int jb = jc * 64 + j4 * 4;
                float4 m4;
                m4 = ld4(&mm[(jb + 0) * 28 + vo]); FMA4(acc0, wa.x, m4); FMA4(acc1, wb.x, m4);
                m4 = ld4(&mm[(jb + 1) * 28 + vo]); FMA4(acc0, wa.y, m4); FMA4(acc1, wb.y, m4);
                m4 = ld4(&mm[(jb + 2) * 28 + vo]); FMA4(acc0, wa.z, m4); FMA4(acc1, wb.z, m4);
                m4 = ld4(&mm[(jb + 3) * 28 + vo]); FMA4(acc0, wa.w, m4); FMA4(acc1, wb.w, m4);
            }
        }
    }
    if (tid < 224) {
        float inv0 = go1[o0] * rsqrtf(vo1[o0] + 1e-5f);
        float bet0 = bo1[o0] - mo1[o0] * inv0;
        float inv1 = go1[oo1] * rsqrtf(vo1[oo1] + 1e-5f);
        float bet1 = bo1[oo1] - mo1[oo1] * inv1;
        float bb0 = b_outs[o0], bb1 = b_outs[oo1];
        float4 r0, r1;
        r0.x = lrelu(xs[o0 * 29 + vo + 0] + (acc0.x + bb0) * inv0 + bet0);
        r0.y = lrelu(xs[o0 * 29 + vo + 1] + (acc0.y + bb0) * inv0 + bet0);
        r0.z = lrelu(xs[o0 * 29 + vo + 2] + (acc0.z + bb0) * inv0 + bet0);
        r0.w = lrelu(xs[o0 * 29 + vo + 3] + (acc0.w + bb0) * inv0 + bet0);
        r1.x = lrelu(xs[oo1 * 29 + vo + 0] + (acc1.x + bb1) * inv1 + bet1);
        r1.y = lrelu(xs[oo1 * 29 + vo + 1] + (acc1.y + bb1) * inv1 + bet1);
        r1.z = lrelu(xs[oo1 * 29 + vo + 2] + (acc1.z + bb1) * inv1 + bet1);
        r1.w = lrelu(xs[oo1 * 29 + vo + 3] + (acc1.w + bb1) * inv1 + bet1);
        st4(&o1[o0 * 28 + vo], r0);
        st4(&o1[oo1 * 28 + vo], r1);
    }
    __syncthreads();
    for (int idx = tid; idx < 4096; idx += 256)
        wbuf[(idx >> 6) * 68 + (idx & 63)] = w_ff[idx];
    __syncthreads();

    // ---- ff stage: tile 2o x 4v, K=64 ----
    if (tid < 224) {
        float4 fa = {0,0,0,0}, fb = {0,0,0,0};
        #pragma unroll
        for (int c4 = 0; c4 < 16; ++c4) {
            float4 wa = ld4(&wbuf[o0 * 68 + c4 * 4]);
            float4 wb = ld4(&wbuf[oo1 * 68 + c4 * 4]);
            const int cb = c4 * 4;
            float4 m4;
            m4 = ld4(&o1[(cb + 0) * 28 + vo]); FMA4(fa, wa.x, m4); FMA4(fb, wb.x, m4);
            m4 = ld4(&o1[(cb + 1) * 28 + vo]); FMA4(fa, wa.y, m4); FMA4(fb, wb.y, m4);
            m4 = ld4(&o1[(cb + 2) * 28 + vo]); FMA4(fa, wa.z, m4); FMA4(fb, wb.z, m4);
            m4 = ld4(&o1[(cb + 3) * 28 + vo]); FMA4(fa, wa.w, m4); FMA4(fb, wb.w, m4);
        }
        float inv0 = gf2[o0] * rsqrtf(vf2[o0] + 1e-5f);
        float bet0 = bf2[o0] - mf2[o0] * inv0;
        float inv1 = gf2[oo1] * rsqrtf(vf2[oo1] + 1e-5f);
        float bet1 = bf2[oo1] - mf2[oo1] * inv1;
        float bb0 = b_ff[o0], bb1 = b_ff[oo1];
        YT* yb0 = &y2out[(n * 64 + o0) * PIX + t * 27];
        YT* yb1 = &y2out[(n * 64 + oo1) * PIX + t * 27];
        float va[4] = {fa.x, fa.y, fa.z, fa.w};
        float vb[4] = {fb.x, fb.y, fb.z, fb.w};
        #pragma unroll
        for (int i = 0; i < 4; ++i) {
            int v = vo + i;
            if (v < 27) {
                st_y(&yb0[v], lrelu(xs[o0 * 29 + v] + (va[i] + bb0) * inv0 + bet0));
                st_y(&yb1[v], lrelu(xs[oo1 * 29 + v] + (vb[i] + bb1) * inv1 + bet1));
            }
        }
    }
}

// ---------------------------------------------------------------------------
// k_tconv: temporal 3x1 conv as GEMM K=192 (kk = c*3+kt), tile 2o x 4v.
// ---------------------------------------------------------------------------
template <typename YT>
__global__ __launch_bounds__(256) void k_tconv(
    const YT* __restrict__ y2in, const float* __restrict__ w_t,
    const float* __restrict__ b_t,
    const float* __restrict__ gt, const float* __restrict__ bt,
    const float* __restrict__ mt, const float* __restrict__ vt,
    float* __restrict__ out)
{
    const int tid = threadIdx.x;
    const int t = blockIdx.x, n = blockIdx.y;

    __shared__ __align__(16) float yf[192 * 28];    // [kk=c*3+kt][28v]
    __shared__ __align__(16) float wbuf[64 * 68];

    for (int idx = tid; idx < 5376; idx += 256) {
        int kk = idx / 28, v = idx - kk * 28;
        int c = kk / 3, kt = kk - c * 3;
        int tt = t + kt - 1;
        yf[idx] = (v < 27 && tt >= 0 && tt < TT)
                    ? ld_y(&y2in[(n * 64 + c) * PIX + tt * 27 + v]) : 0.f;
    }

    const int vg = tid % 7, og = tid / 7;
    const int vo = vg * 4, o0 = og * 2, oo1 = o0 + 1;
    float4 acc0 = {0,0,0,0}, acc1 = {0,0,0,0};

    for (int kc = 0; kc < 3; ++kc) {
        __syncthreads();
        for (int idx = tid; idx < 4096; idx += 256)
            wbuf[(idx >> 6) * 68 + (idx & 63)] = w_t[(idx >> 6) * 192 + kc * 64 + (idx & 63)];
        __syncthreads();
        if (tid < 224) {
            #pragma unroll
            for (int k4 = 0; k4 < 16; ++k4) {
                float4 wa = ld4(&wbuf[o0 * 68 + k4 * 4]);
                float4 wb = ld4(&wbuf[oo1 * 68 + k4 * 4]);
                const int kb = kc * 64 + k4 * 4;
                float4 y4;
                y4 = ld4(&yf[(kb + 0) * 28 + vo]); FMA4(acc0, wa.x, y4); FMA4(acc1, wb.x, y4);
                y4 = ld4(&yf[(kb + 1) * 28 + vo]); FMA4(acc0, wa.y, y4); FMA4(acc1, wb.y, y4);
                y4 = ld4(&yf[(kb + 2) * 28 + vo]); FMA4(acc0, wa.z, y4); FMA4(acc1, wb.z, y4);
                y4 = ld4(&yf[(kb + 3) * 28 + vo]); FMA4(acc0, wa.w, y4); FMA4(acc1, wb.w, y4);
            }
        }
    }
    if (tid < 224) {
        float inv0 = gt[o0] * rsqrtf(vt[o0] + 1e-5f);
        float bet0 = bt[o0] - mt[o0] * inv0;
        float inv1 = gt[oo1] * rsqrtf(vt[oo1] + 1e-5f);
        float bet1 = bt[oo1] - mt[oo1] * inv1;
        float bb0 = b_t[o0], bb1 = b_t[oo1];
        float va[4] = {acc0.x, acc0.y, acc0.z, acc0.w};
        float vb[4] = {acc1.x, acc1.y, acc1.z, acc1.w};
        float* ob0 = &out[(n * 64 + o0) * PIX + t * 27];
        float* ob1 = &out[(n * 64 + oo1) * PIX + t * 27];
        #pragma unroll
        for (int i = 0; i < 4; ++i) {
            int v = vo + i;
            if (v < 27) {
                float res0 = yf[(o0 * 3 + 1) * 28 + v];
                float res1 = yf[(oo1 * 3 + 1) * 28 + v];
                ob0[v] = lrelu(res0 + (va[i] + bb0) * inv0 + bet0);
                ob1[v] = lrelu(res1 + (vb[i] + bb1) * inv1 + bet1);
            }
        }
    }
}

// ---------------------------------------------------------------------------
extern "C" void kernel_launch(void* const* d_in, const int* in_sizes, int n_in,
                              void* d_out, int out_size, void* d_ws, size_t ws_size,
                              hipStream_t stream)
{
    const float* x      = (const float*)d_in[0];
    const float* w_in   = (const float*)d_in[1];
    const float* b_in   = (const float*)d_in[2];
    const float* alphas = (const float*)d_in[3];
    const float* att0   = (const float*)d_in[4];
    const float* w_outs = (const float*)d_in[5];
    const float* b_outs = (const float*)d_in[6];
    const float* bog    = (const float*)d_in[7];
    const float* bob    = (const float*)d_in[8];
    const float* bom    = (const float*)d_in[9];
    const float* bov    = (const float*)d_in[10];
    const float* w_ff   = (const float*)d_in[11];
    const float* b_ff   = (const float*)d_in[12];
    const float* bfg    = (const float*)d_in[13];
    const float* bfb    = (const float*)d_in[14];
    const float* bfm    = (const float*)d_in[15];
    const float* bfv    = (const float*)d_in[16];
    const float* w_t    = (const float*)d_in[17];
    const float* b_t    = (const float*)d_in[18];
    const float* btg    = (const float*)d_in[19];
    const float* btb    = (const float*)d_in[20];
    const float* btm    = (const float*)d_in[21];
    const float* btv    = (const float*)d_in[22];

    // ws layout: pb (1792 f32) | scores (46656) | att (46656) | y2
    float* pbw    = (float*)d_ws;
    float* scores = pbw + 1792;
    float* att    = scores + NSUV;
    void*  y2     = (void*)(att + NSUV);

    const size_t need_f32 = (size_t)(1792 + 2 * NSUV) * 4 + (size_t)XTOT * 4;
    const bool y2_f32 = (ws_size >= need_f32);

    hipMemsetAsync(scores, 0, NSUV * sizeof(float), stream);

    k_pbias<<<1, 256, 0, stream>>>(w_in, b_in, pbw);
    k_scores<<<dim3(25, 2, NN), 256, 0, stream>>>(x, w_in, pbw, scores);
    k_att<<<(NSUV + 255) / 256, 256, 0, stream>>>(scores, alphas, att0, att);
    if (y2_f32) {
        k_cde<float><<<dim3(TT, NN), 256, 0, stream>>>(x, att, w_outs, b_outs,
                                                bog, bob, bom, bov,
                                                w_ff, b_ff, bfg, bfb, bfm, bfv,
                                                (float*)y2);
        k_tconv<float><<<dim3(TT, NN), 256, 0, stream>>>((const float*)y2, w_t, b_t,
                                                btg, btb, btm, btv, (float*)d_out);
    } else {
        k_cde<bf16><<<dim3(TT, NN), 256, 0, stream>>>(x, att, w_outs, b_outs,
                                                bog, bob, bom, bov,
                                                w_ff, b_ff, bfg, bfb, bfm, bfv,
                                                (bf16*)y2);
        k_tconv<bf16><<<dim3(TT, NN), 256, 0, stream>>>((const bf16*)y2, w_t, b_t,
                                                btg, btb, btm, btv, (float*)d_out);
    }
}